// Round 1
// baseline (638.715 us; speedup 1.0000x reference)
//
#include <hip/hip_runtime.h>
#include <hip/hip_bf16.h>

#define N_NODES 100000
#define R_REL   7
#define E_EDGES 1600000
#define EDIM    16
#define NR      (N_NODES * R_REL)   // 700000
#define KTOT    640                 // 448 msg + 64 self + 112 F + 7 sw + 9 pad
#define NB_SCAN 684                 // ceil(700000/1024)

typedef __bf16 bf16_t;
typedef bf16_t bf16x8 __attribute__((ext_vector_type(8)));
typedef float  f32x4  __attribute__((ext_vector_type(4)));

// ---------------- CSR build ----------------

__global__ void k_hist(const int* __restrict__ el, int* __restrict__ cnt) {
    int e = blockIdx.x * 256 + threadIdx.x;
    if (e < E_EDGES) {
        int seg = el[e * 3 + 1] * R_REL + el[e * 3 + 2];
        atomicAdd(&cnt[seg], 1);
    }
}

__global__ void k_scan1(const int* __restrict__ cnt, int* __restrict__ off,
                        int* __restrict__ bsums) {
    __shared__ int s[1024];
    int i = blockIdx.x * 1024 + threadIdx.x;
    int v = (i < NR) ? cnt[i] : 0;
    s[threadIdx.x] = v;
    __syncthreads();
    for (int d = 1; d < 1024; d <<= 1) {
        int t = (threadIdx.x >= d) ? s[threadIdx.x - d] : 0;
        __syncthreads();
        s[threadIdx.x] += t;
        __syncthreads();
    }
    if (i < NR) off[i + 1] = s[threadIdx.x];
    if (threadIdx.x == 1023) bsums[blockIdx.x] = s[1023];
}

__global__ void k_scan2(int* __restrict__ bsums, int nb) {
    __shared__ int s[1024];
    int v = (threadIdx.x < nb) ? bsums[threadIdx.x] : 0;
    s[threadIdx.x] = v;
    __syncthreads();
    for (int d = 1; d < 1024; d <<= 1) {
        int t = (threadIdx.x >= d) ? s[threadIdx.x - d] : 0;
        __syncthreads();
        s[threadIdx.x] += t;
        __syncthreads();
    }
    if (threadIdx.x < nb) bsums[threadIdx.x] = s[threadIdx.x] - v;  // exclusive
}

__global__ void k_scan3(int* __restrict__ off, const int* __restrict__ bsums,
                        int* __restrict__ cursor) {
    int i = blockIdx.x * 1024 + threadIdx.x;
    if (i < NR) {
        int v = off[i + 1] + bsums[blockIdx.x];
        off[i + 1]    = v;
        cursor[i + 1] = v;
    }
    if (i == 0) { off[0] = 0; cursor[0] = 0; }
}

__global__ void k_scatter(const int* __restrict__ el, int* __restrict__ cursor,
                          int* __restrict__ sorted) {
    int e = blockIdx.x * 256 + threadIdx.x;
    if (e < E_EDGES) {
        int seg = el[e * 3 + 1] * R_REL + el[e * 3 + 2];
        int p = atomicAdd(&cursor[seg], 1);
        sorted[p] = e;
    }
}

// ---------------- pack extended-K B operand (bf16, MFMA B-frag friendly) ----
// B[k][j], k in [0,640):
//   k <448        : W_lin[j][k]
//   448..511      : W_self[j][k-448]
//   512..623      : (W_lin_r @ W_edge)[j][kk],  r=(k-512)/16, kk=(k-512)%16
//   624..630      : (W_lin_r @ b_edge)[j],      r=k-624
//   631..639      : 0
// layout: Bp[(k/8)*64 + j)*8 + (k%8)]  -> lane reads 8 contiguous bf16 (16B)

__global__ void k_packB(const float* __restrict__ W_lin, const float* __restrict__ W_self,
                        const float* __restrict__ W_edge, const float* __restrict__ b_edge,
                        bf16_t* __restrict__ Bp) {
    int idx = blockIdx.x * 256 + threadIdx.x;
    if (idx >= KTOT * 64) return;
    int k = idx >> 6;
    int j = idx & 63;
    float v;
    if (k < 448) {
        v = W_lin[j * 448 + k];
    } else if (k < 512) {
        v = W_self[j * 64 + (k - 448)];
    } else if (k < 624) {
        int r = (k - 512) >> 4, kk = (k - 512) & 15;
        float s = 0.f;
        for (int d = 0; d < 64; d++)
            s = fmaf(W_lin[j * 448 + r * 64 + d], W_edge[d * 16 + kk], s);
        v = s;
    } else if (k < 631) {
        int r = k - 624;
        float s = 0.f;
        for (int d = 0; d < 64; d++)
            s = fmaf(W_lin[j * 448 + r * 64 + d], b_edge[d], s);
        v = s;
    } else {
        v = 0.f;
    }
    Bp[((k >> 3) * 64 + j) * 8 + (k & 7)] = (bf16_t)v;
}

// ---------------- fused gather/segment-sum + MFMA GEMM ----------------
// block = 256 thr (4 waves) = 16 nodes. N = 6250 * 16 exactly.
// Stage 1: wave w accumulates rows w*4..w*4+3 of the LDS A-tile (K=640, bf16).
// Stage 2: wave w computes C[16 nodes x 16 j] for j-tile w via 20 MFMA k-steps.

__global__ __launch_bounds__(256) void k_main(
    const float* __restrict__ x, const int* __restrict__ el,
    const float* __restrict__ wgt, const float* __restrict__ ef,
    const float* __restrict__ b_lin, const float* __restrict__ b_self,
    const int* __restrict__ off, const int* __restrict__ sorted,
    const bf16_t* __restrict__ Bp, float* __restrict__ out)
{
    __shared__ __align__(16) bf16_t A[16 * KTOT];  // 20 KB
    const int wave = threadIdx.x >> 6;
    const int lane = threadIdx.x & 63;
    const int nodeBase = blockIdx.x * 16;

    for (int i = 0; i < 4; i++) {
        const int row = wave * 4 + i;
        const int n = nodeBase + row;
        bf16_t* Ar = A + row * KTOT;
        // self-term slot: A[n][448+d] = x[n][d]
        Ar[448 + lane] = (bf16_t)x[n * 64 + lane];
#pragma unroll
        for (int r = 0; r < R_REL; r++) {
            const int seg = n * R_REL + r;
            int lo = __builtin_amdgcn_readfirstlane(off[seg]);
            int hi = __builtin_amdgcn_readfirstlane(off[seg + 1]);
            float acc = 0.f, F = 0.f, sw = 0.f;
            for (int p = lo; p < hi; p++) {
                int e   = __builtin_amdgcn_readfirstlane(sorted[p]);
                int src = __builtin_amdgcn_readfirstlane(el[e * 3]);
                float w = wgt[e];
                acc = fmaf(w, x[src * 64 + lane], acc);       // lane d: msg dim d
                if (lane < EDIM) F = fmaf(w, ef[e * EDIM + lane], F);
                sw += w;
            }
            Ar[r * 64 + lane] = (bf16_t)acc;                   // U_x part
            if (lane < EDIM) Ar[512 + r * EDIM + lane] = (bf16_t)F;  // F part
            if (lane == 0)   Ar[624 + r] = (bf16_t)sw;               // sw part
        }
        if (lane < 9) Ar[631 + lane] = (bf16_t)0.f;            // pad
    }
    __syncthreads();

    const int quad = lane >> 4;
    const int l15  = lane & 15;
    f32x4 c = {0.f, 0.f, 0.f, 0.f};
#pragma unroll
    for (int s = 0; s < KTOT / 32; s++) {
        // A frag: row m = l15 (node), k = s*32 + quad*8 + [0..8)
        bf16x8 a = *(const bf16x8*)(A + l15 * KTOT + s * 32 + quad * 8);
        // B frag: k = s*32 + quad*8 + [0..8), col n = wave*16 + l15
        bf16x8 b = *(const bf16x8*)(Bp + (((s * 4 + quad) * 64) + wave * 16 + l15) * 8);
        c = __builtin_amdgcn_mfma_f32_16x16x32_bf16(a, b, c, 0, 0, 0);
    }
    // C/D layout: col = lane&15, row = quad*4 + reg
    const int j = wave * 16 + l15;
    const float bias = b_lin[j] + b_self[j];
#pragma unroll
    for (int q = 0; q < 4; q++) {
        const int n = nodeBase + quad * 4 + q;
        float v = c[q] + bias;
        out[n * 64 + j] = v > 0.f ? v : 0.f;
    }
}

// ---------------- launch ----------------

extern "C" void kernel_launch(void* const* d_in, const int* in_sizes, int n_in,
                              void* d_out, int out_size, void* d_ws, size_t ws_size,
                              hipStream_t stream) {
    const float* x      = (const float*)d_in[0];
    const int*   el     = (const int*)  d_in[1];
    const float* wgt    = (const float*)d_in[2];
    const float* ef     = (const float*)d_in[3];
    const float* W_lin  = (const float*)d_in[4];
    const float* b_lin  = (const float*)d_in[5];
    const float* W_self = (const float*)d_in[6];
    const float* b_self = (const float*)d_in[7];
    const float* W_edge = (const float*)d_in[8];
    const float* b_edge = (const float*)d_in[9];
    float* out = (float*)d_out;

    // workspace layout (16B-aligned regions), total ~12.1 MB
    int* off    = (int*)d_ws;            // 700016 ints
    int* cursor = off    + 700016;       // 700016 ints
    int* sorted = cursor + 700016;       // 1600000 ints
    int* bsums  = sorted + 1600000;      // 1024 ints
    bf16_t* Bp  = (bf16_t*)(bsums + 1024);  // 640*64 bf16 = 80 KB

    hipMemsetAsync(cursor, 0, (size_t)NR * sizeof(int), stream);
    k_hist   <<<6250, 256, 0, stream>>>(el, cursor);
    k_scan1  <<<NB_SCAN, 1024, 0, stream>>>(cursor, off, bsums);
    k_scan2  <<<1, 1024, 0, stream>>>(bsums, NB_SCAN);
    k_scan3  <<<NB_SCAN, 1024, 0, stream>>>(off, bsums, cursor);
    k_scatter<<<6250, 256, 0, stream>>>(el, cursor, sorted);
    k_packB  <<<(KTOT * 64 + 255) / 256, 256, 0, stream>>>(W_lin, W_self, W_edge, b_edge, Bp);
    k_main   <<<N_NODES / 16, 256, 0, stream>>>(x, el, wgt, ef, b_lin, b_self,
                                                off, sorted, Bp, out);
}

// Round 2
// 490.376 us; speedup vs baseline: 1.3025x; 1.3025x over previous
//
#include <hip/hip_runtime.h>
#include <hip/hip_bf16.h>

#define N_NODES 100000
#define R_REL   7
#define E_EDGES 1600000
#define EDIM    16
#define KTOT    640                 // 448 msg + 64 self + 112 F + 7 sw + 9 pad
#define NB_SCAN 98                  // ceil(100000/1024)

typedef __bf16 bf16_t;
typedef bf16_t bf16x8 __attribute__((ext_vector_type(8)));
typedef float  f32x4  __attribute__((ext_vector_type(4)));

// ---------------- CSR build (by destination NODE, relation kept in record) --

__global__ void k_hist(const int* __restrict__ el, int* __restrict__ cnt) {
    int e = blockIdx.x * 256 + threadIdx.x;
    if (e < E_EDGES) atomicAdd(&cnt[el[e * 3 + 1]], 1);
}

__global__ void k_scan1(const int* __restrict__ cnt, int* __restrict__ off,
                        int* __restrict__ bsums) {
    __shared__ int s[1024];
    int i = blockIdx.x * 1024 + threadIdx.x;
    int v = (i < N_NODES) ? cnt[i] : 0;
    s[threadIdx.x] = v;
    __syncthreads();
    for (int d = 1; d < 1024; d <<= 1) {
        int t = (threadIdx.x >= d) ? s[threadIdx.x - d] : 0;
        __syncthreads();
        s[threadIdx.x] += t;
        __syncthreads();
    }
    if (i < N_NODES) off[i + 1] = s[threadIdx.x];
    if (threadIdx.x == 1023) bsums[blockIdx.x] = s[1023];
}

__global__ void k_scan2(int* __restrict__ bsums, int nb) {
    __shared__ int s[1024];
    int v = (threadIdx.x < nb) ? bsums[threadIdx.x] : 0;
    s[threadIdx.x] = v;
    __syncthreads();
    for (int d = 1; d < 1024; d <<= 1) {
        int t = (threadIdx.x >= d) ? s[threadIdx.x - d] : 0;
        __syncthreads();
        s[threadIdx.x] += t;
        __syncthreads();
    }
    if (threadIdx.x < nb) bsums[threadIdx.x] = s[threadIdx.x] - v;  // exclusive
}

__global__ void k_scan3(int* __restrict__ off, const int* __restrict__ bsums,
                        int* __restrict__ cursor) {
    int i = blockIdx.x * 1024 + threadIdx.x;
    if (i < N_NODES) {
        int v = off[i + 1] + bsums[blockIdx.x];
        off[i + 1]    = v;
        cursor[i + 1] = v;
    }
    if (i == 0) { off[0] = 0; cursor[0] = 0; }
}

// record: (src, w_bits, rel, e) — one 16B load gives everything but the gathers
__global__ void k_scatter(const int* __restrict__ el, const float* __restrict__ wgt,
                          int* __restrict__ cursor, int4* __restrict__ recs) {
    int e = blockIdx.x * 256 + threadIdx.x;
    if (e < E_EDGES) {
        int src = el[e * 3], dst = el[e * 3 + 1], rel = el[e * 3 + 2];
        int p = atomicAdd(&cursor[dst], 1);
        recs[p] = make_int4(src, __float_as_int(wgt[e]), rel, e);
    }
}

// ---------------- pack extended-K B operand (unchanged, verified R1) --------
// B[k][j]: k<448 W_lin[j][k]; 448..511 W_self; 512..623 (W_lin_r@W_edge);
// 624..630 (W_lin_r@b_edge); 631..639 zero.
// layout: Bp[((k/8)*64 + j)*8 + (k%8)]

__global__ void k_packB(const float* __restrict__ W_lin, const float* __restrict__ W_self,
                        const float* __restrict__ W_edge, const float* __restrict__ b_edge,
                        bf16_t* __restrict__ Bp) {
    int idx = blockIdx.x * 256 + threadIdx.x;
    if (idx >= KTOT * 64) return;
    int k = idx >> 6;
    int j = idx & 63;
    float v;
    if (k < 448) {
        v = W_lin[j * 448 + k];
    } else if (k < 512) {
        v = W_self[j * 64 + (k - 448)];
    } else if (k < 624) {
        int r = (k - 512) >> 4, kk = (k - 512) & 15;
        float s = 0.f;
        for (int d = 0; d < 64; d++)
            s = fmaf(W_lin[j * 448 + r * 64 + d], W_edge[d * 16 + kk], s);
        v = s;
    } else if (k < 631) {
        int r = k - 624;
        float s = 0.f;
        for (int d = 0; d < 64; d++)
            s = fmaf(W_lin[j * 448 + r * 64 + d], b_edge[d], s);
        v = s;
    } else {
        v = 0.f;
    }
    Bp[((k >> 3) * 64 + j) * 8 + (k & 7)] = (bf16_t)v;
}

// ---------------- fused gather/segment-sum + MFMA GEMM ----------------
// block = 256 thr (4 waves) = 16 nodes. Stage 1: wave w owns rows w*4..w*4+3;
// per row it walks the node's contiguous record run in batches of 4
// (independent loads — no per-edge dependent chain), routing each edge to its
// relation accumulator via a wave-uniform switch (cheap scalar branch).

#define ACCUM(rc, xv, ev)                                                     \
    {                                                                         \
        float w_   = __int_as_float((rc).y);                                  \
        int   rel_ = __builtin_amdgcn_readfirstlane((rc).z);                  \
        switch (rel_) {                                                       \
            case 0: a0 = fmaf(w_, (xv), a0); f0 = fmaf(w_, (ev), f0); s0 += w_; break; \
            case 1: a1 = fmaf(w_, (xv), a1); f1 = fmaf(w_, (ev), f1); s1 += w_; break; \
            case 2: a2 = fmaf(w_, (xv), a2); f2 = fmaf(w_, (ev), f2); s2 += w_; break; \
            case 3: a3 = fmaf(w_, (xv), a3); f3 = fmaf(w_, (ev), f3); s3 += w_; break; \
            case 4: a4 = fmaf(w_, (xv), a4); f4 = fmaf(w_, (ev), f4); s4 += w_; break; \
            case 5: a5 = fmaf(w_, (xv), a5); f5 = fmaf(w_, (ev), f5); s5 += w_; break; \
            default: a6 = fmaf(w_, (xv), a6); f6 = fmaf(w_, (ev), f6); s6 += w_; break; \
        }                                                                     \
    }

__global__ __launch_bounds__(256) void k_main(
    const float* __restrict__ x, const float* __restrict__ ef,
    const float* __restrict__ b_lin, const float* __restrict__ b_self,
    const int* __restrict__ off, const int4* __restrict__ recs,
    const bf16_t* __restrict__ Bp, float* __restrict__ out)
{
    __shared__ __align__(16) bf16_t A[16 * KTOT];  // 20 KB
    const int wave = threadIdx.x >> 6;
    const int lane = threadIdx.x & 63;
    const int lef  = lane & 15;
    const int nodeBase = blockIdx.x * 16;

    for (int i = 0; i < 4; i++) {
        const int row = wave * 4 + i;
        const int n = nodeBase + row;
        bf16_t* Ar = A + row * KTOT;
        Ar[448 + lane] = (bf16_t)x[n * 64 + lane];       // self-term slot

        const int lo = __builtin_amdgcn_readfirstlane(off[n]);
        const int hi = __builtin_amdgcn_readfirstlane(off[n + 1]);
        float a0 = 0.f, a1 = 0.f, a2 = 0.f, a3 = 0.f, a4 = 0.f, a5 = 0.f, a6 = 0.f;
        float f0 = 0.f, f1 = 0.f, f2 = 0.f, f3 = 0.f, f4 = 0.f, f5 = 0.f, f6 = 0.f;
        float s0 = 0.f, s1 = 0.f, s2 = 0.f, s3 = 0.f, s4 = 0.f, s5 = 0.f, s6 = 0.f;

        int p = lo;
        for (; p + 4 <= hi; p += 4) {
            int4 r0 = recs[p];
            int4 r1 = recs[p + 1];
            int4 r2 = recs[p + 2];
            int4 r3 = recs[p + 3];
            float xv0 = x[r0.x * 64 + lane];
            float xv1 = x[r1.x * 64 + lane];
            float xv2 = x[r2.x * 64 + lane];
            float xv3 = x[r3.x * 64 + lane];
            float ev0 = ef[r0.w * EDIM + lef];
            float ev1 = ef[r1.w * EDIM + lef];
            float ev2 = ef[r2.w * EDIM + lef];
            float ev3 = ef[r3.w * EDIM + lef];
            ACCUM(r0, xv0, ev0);
            ACCUM(r1, xv1, ev1);
            ACCUM(r2, xv2, ev2);
            ACCUM(r3, xv3, ev3);
        }
        for (; p < hi; p++) {
            int4 r0 = recs[p];
            float xv0 = x[r0.x * 64 + lane];
            float ev0 = ef[r0.w * EDIM + lef];
            ACCUM(r0, xv0, ev0);
        }

        Ar[0 * 64 + lane] = (bf16_t)a0;
        Ar[1 * 64 + lane] = (bf16_t)a1;
        Ar[2 * 64 + lane] = (bf16_t)a2;
        Ar[3 * 64 + lane] = (bf16_t)a3;
        Ar[4 * 64 + lane] = (bf16_t)a4;
        Ar[5 * 64 + lane] = (bf16_t)a5;
        Ar[6 * 64 + lane] = (bf16_t)a6;
        if (lane < EDIM) {
            Ar[512 + 0 * EDIM + lane] = (bf16_t)f0;
            Ar[512 + 1 * EDIM + lane] = (bf16_t)f1;
            Ar[512 + 2 * EDIM + lane] = (bf16_t)f2;
            Ar[512 + 3 * EDIM + lane] = (bf16_t)f3;
            Ar[512 + 4 * EDIM + lane] = (bf16_t)f4;
            Ar[512 + 5 * EDIM + lane] = (bf16_t)f5;
            Ar[512 + 6 * EDIM + lane] = (bf16_t)f6;
        }
        if (lane == 0) {
            Ar[624 + 0] = (bf16_t)s0;
            Ar[624 + 1] = (bf16_t)s1;
            Ar[624 + 2] = (bf16_t)s2;
            Ar[624 + 3] = (bf16_t)s3;
            Ar[624 + 4] = (bf16_t)s4;
            Ar[624 + 5] = (bf16_t)s5;
            Ar[624 + 6] = (bf16_t)s6;
        }
        if (lane < 9) Ar[631 + lane] = (bf16_t)0.f;
    }
    __syncthreads();

    const int quad = lane >> 4;
    const int l15  = lane & 15;
    f32x4 c = {0.f, 0.f, 0.f, 0.f};
#pragma unroll
    for (int s = 0; s < KTOT / 32; s++) {
        bf16x8 a = *(const bf16x8*)(A + l15 * KTOT + s * 32 + quad * 8);
        bf16x8 b = *(const bf16x8*)(Bp + (((s * 4 + quad) * 64) + wave * 16 + l15) * 8);
        c = __builtin_amdgcn_mfma_f32_16x16x32_bf16(a, b, c, 0, 0, 0);
    }
    const int j = wave * 16 + l15;
    const float bias = b_lin[j] + b_self[j];
#pragma unroll
    for (int q = 0; q < 4; q++) {
        const int n = nodeBase + quad * 4 + q;
        float v = c[q] + bias;
        out[n * 64 + j] = v > 0.f ? v : 0.f;
    }
}

// ---------------- launch ----------------

extern "C" void kernel_launch(void* const* d_in, const int* in_sizes, int n_in,
                              void* d_out, int out_size, void* d_ws, size_t ws_size,
                              hipStream_t stream) {
    const float* x      = (const float*)d_in[0];
    const int*   el     = (const int*)  d_in[1];
    const float* wgt    = (const float*)d_in[2];
    const float* ef     = (const float*)d_in[3];
    const float* W_lin  = (const float*)d_in[4];
    const float* b_lin  = (const float*)d_in[5];
    const float* W_self = (const float*)d_in[6];
    const float* b_self = (const float*)d_in[7];
    const float* W_edge = (const float*)d_in[8];
    const float* b_edge = (const float*)d_in[9];
    float* out = (float*)d_out;

    // workspace layout: records first for 16B alignment; total ~26.5 MB
    int4* recs  = (int4*)d_ws;                    // 1.6M * 16B = 25.6 MB
    int* off    = (int*)(recs + E_EDGES);         // N+1 ints
    int* cursor = off + (N_NODES + 1);            // N+1 ints
    int* bsums  = cursor + (N_NODES + 1);         // 128 ints
    bf16_t* Bp  = (bf16_t*)(bsums + 128);         // 640*64 bf16 = 80 KB

    hipMemsetAsync(cursor, 0, (size_t)N_NODES * sizeof(int), stream);
    k_hist   <<<6250, 256, 0, stream>>>(el, cursor);
    k_scan1  <<<NB_SCAN, 1024, 0, stream>>>(cursor, off, bsums);
    k_scan2  <<<1, 1024, 0, stream>>>(bsums, NB_SCAN);
    k_scan3  <<<NB_SCAN, 1024, 0, stream>>>(off, bsums, cursor);
    k_scatter<<<6250, 256, 0, stream>>>(el, wgt, cursor, recs);
    k_packB  <<<(KTOT * 64 + 255) / 256, 256, 0, stream>>>(W_lin, W_self, W_edge, b_edge, Bp);
    k_main   <<<N_NODES / 16, 256, 0, stream>>>(x, ef, b_lin, b_self,
                                                off, recs, Bp, out);
}